// Round 1
// baseline (46.279 us; speedup 1.0000x reference)
//
#include <hip/hip_runtime.h>

// YOLO loss forward, MI355X.
// predictions: (16384,7,7,30) f32, targets: (16384,7,7,25) f32 -> scalar f32.
// Memory-bound: 176.6 MB read once. Strategy: coalesced float4 -> LDS staging
// (AoS records are 120B/100B, uncoalesceable per-thread), one thread per cell,
// deterministic two-stage reduction through d_ws.

#define TPB 256
#define TILE 256
#define NBLK 1024

constexpr int S2 = 49;               // 7*7
constexpr int BATCH_ = 16384;
constexpr int NCELLS = BATCH_ * S2;  // 802816
constexpr int NTILES = NCELLS / TILE; // 3136 exactly
constexpr int PSTR = 31;             // padded pred stride (gcd(31,32)=1 -> conflict-free)

__device__ __forceinline__ float iou_f(float a0, float a1, float a2, float a3,
                                       float b0, float b1, float b2, float b3) {
    float ax1 = a0 - a2 * 0.5f, ax2 = a0 + a2 * 0.5f;
    float ay1 = a1 - a3 * 0.5f, ay2 = a1 + a3 * 0.5f;
    float bx1 = b0 - b2 * 0.5f, bx2 = b0 + b2 * 0.5f;
    float by1 = b1 - b3 * 0.5f, by2 = b1 + b3 * 0.5f;
    float iw = fmaxf(fminf(ax2, bx2) - fmaxf(ax1, bx1), 0.0f);
    float ih = fmaxf(fminf(ay2, by2) - fmaxf(ay1, by1), 0.0f);
    float inter = iw * ih;
    float aa = fabsf(a2 * a3);
    float ab = fabsf(b2 * b3);
    return inter / (aa + ab - inter + 1e-6f);
}

__global__ __launch_bounds__(TPB, 2) void yolo_partial(
    const float* __restrict__ pred, const float* __restrict__ targ,
    float* __restrict__ part) {
    __shared__ __align__(16) float sp[TILE * PSTR];   // 31744 B
    __shared__ __align__(16) float st[TILE * 25];     // 25600 B
    __shared__ float swr[TPB / 64];

    const int tid = threadIdx.x;
    float lsum = 0.0f;

    for (int tile = blockIdx.x; tile < NTILES; tile += gridDim.x) {
        const float4* p4 = (const float4*)pred + (size_t)tile * (TILE * 30 / 4); // 1920
        const float4* t4 = (const float4*)targ + (size_t)tile * (TILE * 25 / 4); // 1600

        // ---- stage predictions: coalesced float4 global reads, pad-31 LDS scatter
        for (int i = tid; i < TILE * 30 / 4; i += TPB) {
            float4 v = p4[i];
            float vv[4] = {v.x, v.y, v.z, v.w};
            int f = i * 4;
#pragma unroll
            for (int j = 0; j < 4; ++j) {
                int g = f + j;
                int c = g / 30;          // magic-mul
                int ch = g - c * 30;
                sp[c * PSTR + ch] = vv[j];
            }
        }
        // ---- stage targets: contiguous (stride 25 kept, coprime with 32 banks)
        float4* st4 = (float4*)st;
        for (int i = tid; i < TILE * 25 / 4; i += TPB) st4[i] = t4[i];

        __syncthreads();

        // ---- per-cell loss
        const float* P = &sp[tid * PSTR];
        const float* T = &st[tid * 25];

        float pv[30];
#pragma unroll
        for (int k = 0; k < 30; ++k) pv[k] = P[k];

        float cls = 0.0f;
#pragma unroll
        for (int k = 0; k < 20; ++k) {
            float d = pv[k] - T[k];
            cls += d * d;
        }

        float t0 = T[20], t1 = T[21], t2 = T[22], t3 = T[23], t4v = T[24];
        bool obj = (t0 == 1.0f);

        float i1 = iou_f(pv[20], pv[21], pv[22], pv[23], t0, t1, t2, t3);
        float i2 = iou_f(pv[25], pv[26], pv[27], pv[28], t0, t1, t2, t3);
        bool use1 = i1 > i2;

        float r0 = use1 ? pv[20] : pv[25];
        float r1 = use1 ? pv[21] : pv[26];
        float r2 = use1 ? pv[22] : pv[27];
        float r3 = use1 ? pv[23] : pv[28];
        float r4 = use1 ? pv[24] : pv[29];
        float oc = use1 ? pv[29] : pv[24];

        float dx = r0 - t0;
        float dy = r1 - t1;
        float dw = sqrtf(fmaxf(r2, 1e-6f)) - sqrtf(fmaxf(t2, 1e-6f));
        float dh = sqrtf(fmaxf(r3, 1e-6f)) - sqrtf(fmaxf(t3, 1e-6f));
        float coord = 5.0f * (dx * dx + dy * dy + dw * dw + dh * dh);

        float dconf = r4 - t4v;
        float obj_conf = dconf * dconf;

        float noobj_in = 0.5f * oc * oc;
        float noobj_out = 0.5f * (pv[24] * pv[24] + pv[29] * pv[29]);

        lsum += obj ? (coord + obj_conf + cls + noobj_in) : noobj_out;

        __syncthreads();  // protect LDS before next tile's staging
    }

    // ---- block reduction (fixed order -> deterministic)
#pragma unroll
    for (int off = 32; off > 0; off >>= 1) lsum += __shfl_down(lsum, off, 64);
    if ((tid & 63) == 0) swr[tid >> 6] = lsum;
    __syncthreads();
    if (tid == 0) part[blockIdx.x] = swr[0] + swr[1] + swr[2] + swr[3];
}

__global__ __launch_bounds__(TPB) void yolo_reduce(const float* __restrict__ part,
                                                   float* __restrict__ out) {
    __shared__ float swr[TPB / 64];
    const int tid = threadIdx.x;
    float s = 0.0f;
    for (int i = tid; i < NBLK; i += TPB) s += part[i];
#pragma unroll
    for (int off = 32; off > 0; off >>= 1) s += __shfl_down(s, off, 64);
    if ((tid & 63) == 0) swr[tid >> 6] = s;
    __syncthreads();
    if (tid == 0) out[0] = (swr[0] + swr[1] + swr[2] + swr[3]) * (1.0f / 16384.0f);
}

extern "C" void kernel_launch(void* const* d_in, const int* in_sizes, int n_in,
                              void* d_out, int out_size, void* d_ws, size_t ws_size,
                              hipStream_t stream) {
    const float* pred = (const float*)d_in[0];
    const float* targ = (const float*)d_in[1];
    float* part = (float*)d_ws;   // NBLK floats = 4 KB
    float* out = (float*)d_out;

    yolo_partial<<<NBLK, TPB, 0, stream>>>(pred, targ, part);
    yolo_reduce<<<1, TPB, 0, stream>>>(part, out);
}

// Round 2
// 39.730 us; speedup vs baseline: 1.1649x; 1.1649x over previous
//
#include <hip/hip_runtime.h>

// YOLO loss forward, MI355X — round 2.
// predictions: (16384,7,7,30) f32, targets: (16384,7,7,25) f32 -> scalar f32.
// R1 post-mortem: LDS-staged version was occupancy-bound (19%, 2 blocks/CU from
// 57.8KB LDS) + barrier-serialized; HBM at 13%. This version: no LDS, no
// barriers — per-thread direct AoS loads. A wave's 64 cells span contiguous
// 7.5KB (pred) / 6.4KB (targ); L1 merges the strided lane accesses so HBM
// traffic is still exactly the data size. Occupancy becomes VGPR-limited.

#define TPB 256

constexpr int S2 = 49;                 // 7*7
constexpr int BATCH_ = 16384;
constexpr int NCELLS = BATCH_ * S2;    // 802816
constexpr int NBLK = NCELLS / TPB;     // 3136 exactly

__device__ __forceinline__ float iou_f(float a0, float a1, float a2, float a3,
                                       float b0, float b1, float b2, float b3) {
    float ax1 = a0 - a2 * 0.5f, ax2 = a0 + a2 * 0.5f;
    float ay1 = a1 - a3 * 0.5f, ay2 = a1 + a3 * 0.5f;
    float bx1 = b0 - b2 * 0.5f, bx2 = b0 + b2 * 0.5f;
    float by1 = b1 - b3 * 0.5f, by2 = b1 + b3 * 0.5f;
    float iw = fmaxf(fminf(ax2, bx2) - fmaxf(ax1, bx1), 0.0f);
    float ih = fmaxf(fminf(ay2, by2) - fmaxf(ay1, by1), 0.0f);
    float inter = iw * ih;
    float aa = fabsf(a2 * a3);
    float ab = fabsf(b2 * b3);
    return inter / (aa + ab - inter + 1e-6f);
}

__global__ __launch_bounds__(TPB, 4) void yolo_cell(
    const float* __restrict__ pred, const float* __restrict__ targ,
    float* __restrict__ part) {
    __shared__ float swr[TPB / 64];

    const int tid = threadIdx.x;
    const int cell = blockIdx.x * TPB + tid;   // always < NCELLS (exact grid)

    // pred: 30 floats at byte offset cell*120 (8B-aligned) -> 15x float2
    const float2* p2 = (const float2*)(pred + (size_t)cell * 30);
    float pv[30];
#pragma unroll
    for (int k = 0; k < 15; ++k) {
        float2 v = p2[k];
        pv[2 * k]     = v.x;
        pv[2 * k + 1] = v.y;
    }

    // targ: 25 floats at byte offset cell*100 (only 4B-aligned) -> scalar loads
    const float* T = targ + (size_t)cell * 25;
    float tv[25];
#pragma unroll
    for (int k = 0; k < 25; ++k) tv[k] = T[k];

    // ---- per-cell loss
    float cls = 0.0f;
#pragma unroll
    for (int k = 0; k < 20; ++k) {
        float d = pv[k] - tv[k];
        cls += d * d;
    }

    float t0 = tv[20], t1 = tv[21], t2 = tv[22], t3 = tv[23], t4v = tv[24];
    bool obj = (t0 == 1.0f);

    float i1 = iou_f(pv[20], pv[21], pv[22], pv[23], t0, t1, t2, t3);
    float i2 = iou_f(pv[25], pv[26], pv[27], pv[28], t0, t1, t2, t3);
    bool use1 = i1 > i2;

    float r0 = use1 ? pv[20] : pv[25];
    float r1 = use1 ? pv[21] : pv[26];
    float r2 = use1 ? pv[22] : pv[27];
    float r3 = use1 ? pv[23] : pv[28];
    float r4 = use1 ? pv[24] : pv[29];
    float oc = use1 ? pv[29] : pv[24];

    float dx = r0 - t0;
    float dy = r1 - t1;
    float dw = sqrtf(fmaxf(r2, 1e-6f)) - sqrtf(fmaxf(t2, 1e-6f));
    float dh = sqrtf(fmaxf(r3, 1e-6f)) - sqrtf(fmaxf(t3, 1e-6f));
    float coord = 5.0f * (dx * dx + dy * dy + dw * dw + dh * dh);

    float dconf = r4 - t4v;
    float obj_conf = dconf * dconf;

    float noobj_in = 0.5f * oc * oc;
    float noobj_out = 0.5f * (pv[24] * pv[24] + pv[29] * pv[29]);

    float lsum = obj ? (coord + obj_conf + cls + noobj_in) : noobj_out;

    // ---- block reduction (fixed order -> deterministic)
#pragma unroll
    for (int off = 32; off > 0; off >>= 1) lsum += __shfl_down(lsum, off, 64);
    if ((tid & 63) == 0) swr[tid >> 6] = lsum;
    __syncthreads();
    if (tid == 0) part[blockIdx.x] = swr[0] + swr[1] + swr[2] + swr[3];
}

__global__ __launch_bounds__(TPB) void yolo_reduce(const float* __restrict__ part,
                                                   float* __restrict__ out) {
    __shared__ float swr[TPB / 64];
    const int tid = threadIdx.x;
    float s = 0.0f;
    for (int i = tid; i < NBLK; i += TPB) s += part[i];
#pragma unroll
    for (int off = 32; off > 0; off >>= 1) s += __shfl_down(s, off, 64);
    if ((tid & 63) == 0) swr[tid >> 6] = s;
    __syncthreads();
    if (tid == 0) out[0] = (swr[0] + swr[1] + swr[2] + swr[3]) * (1.0f / 16384.0f);
}

extern "C" void kernel_launch(void* const* d_in, const int* in_sizes, int n_in,
                              void* d_out, int out_size, void* d_ws, size_t ws_size,
                              hipStream_t stream) {
    const float* pred = (const float*)d_in[0];
    const float* targ = (const float*)d_in[1];
    float* part = (float*)d_ws;   // NBLK floats ~ 12.5 KB
    float* out = (float*)d_out;

    yolo_cell<<<NBLK, TPB, 0, stream>>>(pred, targ, part);
    yolo_reduce<<<1, TPB, 0, stream>>>(part, out);
}

// Round 3
// 35.702 us; speedup vs baseline: 1.2963x; 1.1128x over previous
//
#include <hip/hip_runtime.h>

// YOLO loss forward, MI355X — round 3.
// R2 post-mortem: per-thread AoS scatter loads are TA/transaction-bound
// (~3 B/cyc/CU useful). Fix: coalesced global_load_lds staging into per-wave
// double-buffered LDS with counted vmcnt (no barriers; each wave owns its own
// 64 cells + LDS region). Identity LDS layout (region byte-copy), widths 16/4.

#define TPB 256
#define GRID 224
#define NITER 14

constexpr int NCELLS = 16384 * 49;      // 802816 = 224*256*14 exactly
constexpr int CSTRIDE = GRID * TPB;     // 57344 cells per grid step
constexpr int NPART = GRID * 4;         // 896 per-wave partials

#define GP(x) ((const __attribute__((address_space(1))) void*)(x))
#define LP(x) ((__attribute__((address_space(3))) void*)(x))

__device__ __forceinline__ void stage_wave(const float* __restrict__ pred,
                                           const float* __restrict__ targ,
                                           int cb, int l,
                                           float* spw, float* stw) {
    // wave-contiguous regions, both 16B-aligned (cb % 64 == 0)
    const char* ps = (const char*)pred + (size_t)cb * 120;  // 7680 B
    const char* ts = (const char*)targ + (size_t)cb * 100;  // 6400 B
#pragma unroll
    for (int j = 0; j < 7; ++j)   // 7*1024 = 7168 B
        __builtin_amdgcn_global_load_lds(GP(ps + j * 1024 + l * 16), LP(spw + j * 256), 16, 0, 0);
    __builtin_amdgcn_global_load_lds(GP(ps + 7168 + l * 4), LP(spw + 1792), 4, 0, 0);
    __builtin_amdgcn_global_load_lds(GP(ps + 7424 + l * 4), LP(spw + 1856), 4, 0, 0);
#pragma unroll
    for (int j = 0; j < 6; ++j)   // 6*1024 = 6144 B
        __builtin_amdgcn_global_load_lds(GP(ts + j * 1024 + l * 16), LP(stw + j * 256), 16, 0, 0);
    __builtin_amdgcn_global_load_lds(GP(ts + 6144 + l * 4), LP(stw + 1536), 4, 0, 0);
    // 16 VMEM instructions total
}

__device__ __forceinline__ float iou_f(float a0, float a1, float a2, float a3,
                                       float b0, float b1, float b2, float b3) {
    float ax1 = a0 - a2 * 0.5f, ax2 = a0 + a2 * 0.5f;
    float ay1 = a1 - a3 * 0.5f, ay2 = a1 + a3 * 0.5f;
    float bx1 = b0 - b2 * 0.5f, bx2 = b0 + b2 * 0.5f;
    float by1 = b1 - b3 * 0.5f, by2 = b1 + b3 * 0.5f;
    float iw = fmaxf(fminf(ax2, bx2) - fmaxf(ax1, bx1), 0.0f);
    float ih = fmaxf(fminf(ay2, by2) - fmaxf(ay1, by1), 0.0f);
    float inter = iw * ih;
    float aa = fabsf(a2 * a3);
    float ab = fabsf(b2 * b3);
    return inter / (aa + ab - inter + 1e-6f);
}

__global__ __launch_bounds__(TPB) void yolo_cell(
    const float* __restrict__ pred, const float* __restrict__ targ,
    float* __restrict__ part) {
    __shared__ float sp[4][2][1920];   // per-wave pred buffers (61440 B)
    __shared__ float st[4][2][1600];   // per-wave targ buffers (51200 B)

    const int tid = threadIdx.x;
    const int w = tid >> 6;
    const int l = tid & 63;
    const int cb0 = blockIdx.x * TPB + w * 64;   // wave's first tile base cell

    float lsum = 0.0f;

    // prologue: stage tile 0 into buffer 0
    stage_wave(pred, targ, cb0, l, &sp[w][0][0], &st[w][0][0]);

#pragma unroll 1
    for (int k = 0; k < NITER; ++k) {
        const int cur = k & 1;
        if (k + 1 < NITER) {
            stage_wave(pred, targ, cb0 + (k + 1) * CSTRIDE, l,
                       &sp[w][cur ^ 1][0], &st[w][cur ^ 1][0]);
            asm volatile("s_waitcnt vmcnt(16)" ::: "memory");  // tile k resident, k+1 in flight
        } else {
            asm volatile("s_waitcnt vmcnt(0)" ::: "memory");
        }
        __builtin_amdgcn_sched_barrier(0);

        const float* spw = &sp[w][cur][0];
        const float* stw = &st[w][cur][0];

        // identity layout: this thread's cell = cb + l -> local floats l*30 / l*25
        const float2* p2 = (const float2*)(spw + l * 30);   // 8B-aligned
        float pv[30];
#pragma unroll
        for (int j = 0; j < 15; ++j) {
            float2 v = p2[j];
            pv[2 * j]     = v.x;
            pv[2 * j + 1] = v.y;
        }
        const float* T = stw + l * 25;
        float tv[25];
#pragma unroll
        for (int j = 0; j < 25; ++j) tv[j] = T[j];

        float cls = 0.0f;
#pragma unroll
        for (int j = 0; j < 20; ++j) {
            float d = pv[j] - tv[j];
            cls += d * d;
        }

        float t0 = tv[20], t1 = tv[21], t2 = tv[22], t3 = tv[23], t4v = tv[24];
        bool obj = (t0 == 1.0f);

        float i1 = iou_f(pv[20], pv[21], pv[22], pv[23], t0, t1, t2, t3);
        float i2 = iou_f(pv[25], pv[26], pv[27], pv[28], t0, t1, t2, t3);
        bool use1 = i1 > i2;

        float r0 = use1 ? pv[20] : pv[25];
        float r1 = use1 ? pv[21] : pv[26];
        float r2 = use1 ? pv[22] : pv[27];
        float r3 = use1 ? pv[23] : pv[28];
        float r4 = use1 ? pv[24] : pv[29];
        float oc = use1 ? pv[29] : pv[24];

        float dx = r0 - t0;
        float dy = r1 - t1;
        float dw = sqrtf(fmaxf(r2, 1e-6f)) - sqrtf(fmaxf(t2, 1e-6f));
        float dh = sqrtf(fmaxf(r3, 1e-6f)) - sqrtf(fmaxf(t3, 1e-6f));
        float coord = 5.0f * (dx * dx + dy * dy + dw * dw + dh * dh);

        float dconf = r4 - t4v;
        float obj_conf = dconf * dconf;

        float noobj_in = 0.5f * oc * oc;
        float noobj_out = 0.5f * (pv[24] * pv[24] + pv[29] * pv[29]);

        lsum += obj ? (coord + obj_conf + cls + noobj_in) : noobj_out;

        // fence: all ds_reads of this tile retired before next iter's staging
        // can overwrite this buffer (and block compiler from sinking reads).
        asm volatile("s_waitcnt lgkmcnt(0)" ::: "memory");
    }

    // per-wave reduction (fixed order -> deterministic), no cross-wave sync
#pragma unroll
    for (int off = 32; off > 0; off >>= 1) lsum += __shfl_down(lsum, off, 64);
    if (l == 0) part[blockIdx.x * 4 + w] = lsum;
}

__global__ __launch_bounds__(TPB) void yolo_reduce(const float* __restrict__ part,
                                                   float* __restrict__ out) {
    __shared__ float swr[TPB / 64];
    const int tid = threadIdx.x;
    float s = 0.0f;
    for (int i = tid; i < NPART; i += TPB) s += part[i];
#pragma unroll
    for (int off = 32; off > 0; off >>= 1) s += __shfl_down(s, off, 64);
    if ((tid & 63) == 0) swr[tid >> 6] = s;
    __syncthreads();
    if (tid == 0) out[0] = (swr[0] + swr[1] + swr[2] + swr[3]) * (1.0f / 16384.0f);
}

extern "C" void kernel_launch(void* const* d_in, const int* in_sizes, int n_in,
                              void* d_out, int out_size, void* d_ws, size_t ws_size,
                              hipStream_t stream) {
    const float* pred = (const float*)d_in[0];
    const float* targ = (const float*)d_in[1];
    float* part = (float*)d_ws;   // NPART floats = 3.5 KB
    float* out = (float*)d_out;

    yolo_cell<<<GRID, TPB, 0, stream>>>(pred, targ, part);
    yolo_reduce<<<1, TPB, 0, stream>>>(part, out);
}

// Round 4
// 34.713 us; speedup vs baseline: 1.3332x; 1.0285x over previous
//
#include <hip/hip_runtime.h>

// YOLO loss forward, MI355X — round 4.
// R3 post-mortem: per-wave double-buffer + vmcnt-counted pipeline collapsed
// occupancy to 1 block/CU (4 waves) and serialized each wave (depth-1 pipe,
// full drain per iter) -> latency-bound at 17% HBM. This round: keep the
// coalesced global_load_lds staging (FETCH == ideal 86MB), but use ONE
// 256-cell tile per block, no loop, single barrier, 56.3KB LDS -> 2 blocks/CU,
// 3136 streaming blocks. Overlap comes from co-resident + successive blocks.

#define TPB 256
#define NBLK 3136                     // 802816 cells / 256 per block, exact

constexpr int NPART = NBLK;

#define GP(x) ((const __attribute__((address_space(1))) void*)(x))
#define LP(x) ((__attribute__((address_space(3))) void*)(x))

__device__ __forceinline__ float iou_f(float a0, float a1, float a2, float a3,
                                       float b0, float b1, float b2, float b3) {
    float ax1 = a0 - a2 * 0.5f, ax2 = a0 + a2 * 0.5f;
    float ay1 = a1 - a3 * 0.5f, ay2 = a1 + a3 * 0.5f;
    float bx1 = b0 - b2 * 0.5f, bx2 = b0 + b2 * 0.5f;
    float by1 = b1 - b3 * 0.5f, by2 = b1 + b3 * 0.5f;
    float iw = fmaxf(fminf(ax2, bx2) - fmaxf(ax1, bx1), 0.0f);
    float ih = fmaxf(fminf(ay2, by2) - fmaxf(ay1, by1), 0.0f);
    float inter = iw * ih;
    float aa = fabsf(a2 * a3);
    float ab = fabsf(b2 * b3);
    return inter / (aa + ab - inter + 1e-6f);
}

__global__ __launch_bounds__(TPB, 2) void yolo_cell(
    const float* __restrict__ pred, const float* __restrict__ targ,
    float* __restrict__ part) {
    __shared__ __align__(16) float sp[TPB * 30];   // 30720 B, [256][30] packed
    __shared__ __align__(16) float st[TPB * 25];   // 25600 B, [256][25] packed
    __shared__ float swr[4];

    const int tid = threadIdx.x;
    const int w = tid >> 6;
    const int l = tid & 63;

    // ---- stage this block's 256 cells, fully coalesced, identity LDS layout
    const char* ps = (const char*)pred + (size_t)blockIdx.x * (TPB * 120); // 30720 B
    const char* ts = (const char*)targ + (size_t)blockIdx.x * (TPB * 100); // 25600 B

#pragma unroll
    for (int j = 0; j < 7; ++j)        // 7 * 4096 = 28672 B of pred
        __builtin_amdgcn_global_load_lds(GP(ps + j * 4096 + w * 1024 + l * 16),
                                         LP((char*)sp + j * 4096 + w * 1024), 16, 0, 0);
#pragma unroll
    for (int j = 0; j < 2; ++j)        // remaining 2048 B of pred (width 4)
        __builtin_amdgcn_global_load_lds(GP(ps + 28672 + j * 1024 + w * 256 + l * 4),
                                         LP((char*)sp + 28672 + j * 1024 + w * 256), 4, 0, 0);
#pragma unroll
    for (int j = 0; j < 6; ++j)        // 6 * 4096 = 24576 B of targ
        __builtin_amdgcn_global_load_lds(GP(ts + j * 4096 + w * 1024 + l * 16),
                                         LP((char*)st + j * 4096 + w * 1024), 16, 0, 0);
    __builtin_amdgcn_global_load_lds(GP(ts + 24576 + w * 256 + l * 4),
                                     LP((char*)st + 24576 + w * 256), 4, 0, 0);

    asm volatile("s_waitcnt vmcnt(0)" ::: "memory");
    __syncthreads();

    // ---- per-cell loss from LDS
    const float2* p2 = (const float2*)(sp + tid * 30);  // 8B-aligned (30 even)
    float pv[30];
#pragma unroll
    for (int j = 0; j < 15; ++j) {
        float2 v = p2[j];
        pv[2 * j]     = v.x;
        pv[2 * j + 1] = v.y;
    }
    const float* T = st + tid * 25;
    float tv[25];
#pragma unroll
    for (int j = 0; j < 25; ++j) tv[j] = T[j];

    float cls = 0.0f;
#pragma unroll
    for (int j = 0; j < 20; ++j) {
        float d = pv[j] - tv[j];
        cls += d * d;
    }

    float t0 = tv[20], t1 = tv[21], t2 = tv[22], t3 = tv[23], t4v = tv[24];
    bool obj = (t0 == 1.0f);

    float i1 = iou_f(pv[20], pv[21], pv[22], pv[23], t0, t1, t2, t3);
    float i2 = iou_f(pv[25], pv[26], pv[27], pv[28], t0, t1, t2, t3);
    bool use1 = i1 > i2;

    float r0 = use1 ? pv[20] : pv[25];
    float r1 = use1 ? pv[21] : pv[26];
    float r2 = use1 ? pv[22] : pv[27];
    float r3 = use1 ? pv[23] : pv[28];
    float r4 = use1 ? pv[24] : pv[29];
    float oc = use1 ? pv[29] : pv[24];

    float dx = r0 - t0;
    float dy = r1 - t1;
    float dw = sqrtf(fmaxf(r2, 1e-6f)) - sqrtf(fmaxf(t2, 1e-6f));
    float dh = sqrtf(fmaxf(r3, 1e-6f)) - sqrtf(fmaxf(t3, 1e-6f));
    float coord = 5.0f * (dx * dx + dy * dy + dw * dw + dh * dh);

    float dconf = r4 - t4v;
    float obj_conf = dconf * dconf;

    float noobj_in = 0.5f * oc * oc;
    float noobj_out = 0.5f * (pv[24] * pv[24] + pv[29] * pv[29]);

    float lsum = obj ? (coord + obj_conf + cls + noobj_in) : noobj_out;

    // ---- block reduction (fixed order -> deterministic)
#pragma unroll
    for (int off = 32; off > 0; off >>= 1) lsum += __shfl_down(lsum, off, 64);
    if (l == 0) swr[w] = lsum;
    __syncthreads();
    if (tid == 0) part[blockIdx.x] = swr[0] + swr[1] + swr[2] + swr[3];
}

__global__ __launch_bounds__(TPB) void yolo_reduce(const float* __restrict__ part,
                                                   float* __restrict__ out) {
    __shared__ float swr[TPB / 64];
    const int tid = threadIdx.x;
    float s = 0.0f;
    for (int i = tid; i < NPART; i += TPB) s += part[i];
#pragma unroll
    for (int off = 32; off > 0; off >>= 1) s += __shfl_down(s, off, 64);
    if ((tid & 63) == 0) swr[tid >> 6] = s;
    __syncthreads();
    if (tid == 0) out[0] = (swr[0] + swr[1] + swr[2] + swr[3]) * (1.0f / 16384.0f);
}

extern "C" void kernel_launch(void* const* d_in, const int* in_sizes, int n_in,
                              void* d_out, int out_size, void* d_ws, size_t ws_size,
                              hipStream_t stream) {
    const float* pred = (const float*)d_in[0];
    const float* targ = (const float*)d_in[1];
    float* part = (float*)d_ws;   // NPART floats = 12.5 KB
    float* out = (float*)d_out;

    yolo_cell<<<NBLK, TPB, 0, stream>>>(pred, targ, part);
    yolo_reduce<<<1, TPB, 0, stream>>>(part, out);
}